// Round 13
// baseline (563.566 us; speedup 1.0000x reference)
//
#include <hip/hip_runtime.h>

// CentroidPool: N=65536 x K=4096 x D=128 fp32 -> argmin_k ||x - c_k|| (int32).
// Stage 1: f16x3-split MFMA GEMM (xh*ch + xh*cl + xl*ch, fp32 acc = c2 init),
//   top-2 via sortable packed keys, register ping-pong B pipeline, B pre-packed
//   in per-(tile,step,lane) fragment order -> every B load 64x16B coalesced.
// ROUND-26: MB 64 -> 128 rows per block. Per-kt fixed cost (16 B-loads, addr,
//   cvec, c2 prefetch, loop control ~500-700 cyc of the 3110-cyc kt-slot) is
//   row-count-independent -- every B fragment feeds all rows through the MFMA
//   A-operand. Doubling rows halves that cost per point. Register math: accs
//   32->64, b1/b2 16->32, peak liveness ~190 < the 256-reg tier we already
//   occupy half-empty (152) -> same 2 waves/SIMD, NO occupancy loss (the
//   {64,128,256} tier quantization that killed r14-r21 now works FOR us).
//   LDS 73.7KB -> 2 blocks/CU (147KB). Grid 512. INS min3/med3 form (r25),
//   branchless loop (r25), gap-gated fused fp64 rescore (r24) kept.
// Output written directly by argmin blocks.

typedef _Float16 f16;
typedef f16  f16x4 __attribute__((ext_vector_type(4)));
typedef f16  f16x8 __attribute__((ext_vector_type(8)));
typedef float f32x4 __attribute__((ext_vector_type(4)));

constexpr int N_PTS  = 65536;
constexpr int K_CENT = 4096;
constexpr int D_DIM  = 128;
constexpr int MB     = 128;    // points per block (4 waves share them)
constexpr int KW     = 1024;   // centroids per wave (waves split K 4-ways)
constexpr float SOFF = 256.0f; // score offset => strictly positive scores
constexpr unsigned GAP_ULP = 2048u; // rescore-skip margin (see r24 note)

// ---------------------------------------------------------------------------
// Split coords to f16 h/l, pack into fragment order, compute c2+SOFF.
// Vectorized: one float4 (4 dims of one cent) per thread.
// dst = ((gt*4 + ds)*2 + n)*512 + lane*8 + j, j0 = d0&7 in {0,4} -> f16x4.
// c2: 32 threads per cent, pure shuffle reduce (masks 1..16 stay in-group).
// ---------------------------------------------------------------------------
__global__ __launch_bounds__(256) void split_pack_c2(const float* __restrict__ c,
                                                     f16* __restrict__ chp,
                                                     f16* __restrict__ clp,
                                                     float* __restrict__ c2b) {
    const int t = threadIdx.x;
    const int idx = blockIdx.x * 256 + t;      // float4 index over K*D/4
    const int cent = idx >> 5;                 // 32 float4 per cent
    const int d0 = (idx & 31) * 4;             // starting dim
    float4 v = *(const float4*)(c + (size_t)cent * D_DIM + d0);
    f16 h0 = (f16)v.x, h1 = (f16)v.y, h2 = (f16)v.z, h3 = (f16)v.w;
    f16 l0 = (f16)(v.x - (float)h0), l1 = (f16)(v.y - (float)h1);
    f16 l2 = (f16)(v.z - (float)h2), l3 = (f16)(v.w - (float)h3);
    int gt = cent >> 5, n = (cent >> 4) & 1, l15c = cent & 15;
    int ds = d0 >> 5, quad = (d0 >> 3) & 3, j0 = d0 & 7;
    int lane = quad * 16 + l15c;
    int dst = ((gt * 4 + ds) * 2 + n) * 512 + lane * 8 + j0;
    *(f16x4*)(chp + dst) = (f16x4){h0, h1, h2, h3};
    *(f16x4*)(clp + dst) = (f16x4){l0, l1, l2, l3};
    // c2 reduction across the cent's 32 threads.
    float s = v.x * v.x + v.y * v.y + v.z * v.z + v.w * v.w;
#pragma unroll
    for (int m = 1; m < 32; m <<= 1) s += __shfl_xor(s, m, 64);
    if ((t & 31) == 0) c2b[cent] = s + SOFF;
}

// ---------------------------------------------------------------------------
// Stage 1 + fused rescore. Block = 4 waves x 128 points; latent (-2x) split
// h/l in XOR-swizzled LDS. Wave w scans cents [w*1024,(w+1)*1024) in 32-wide
// k-tiles (2 n-groups). Ping-pong invariant: Ba = (kt, ds0), offB -> (kt,ds1).
// key = (bits(score)&~63)|kn, kn = kt*2+n (6b); cent = (wave*64+kn)*16 + l15.
// Acc a<g><n>: row-group g (rows g*16+quad*4+reg), n-group n. 16 f32x4 accs.
// Epilogue: t<128 merges block top-2; gap>GAP_ULP proves top-1 -> write it,
// else exact fp64 rescore (tie -> smaller index).
// ---------------------------------------------------------------------------
__global__ __launch_bounds__(256, 2) void argmin_mfma(
        const float* __restrict__ latent,
        const float* __restrict__ coords,
        const f16*   __restrict__ chp,    // packed B hi
        const f16*   __restrict__ clp,    // packed B lo
        const float* __restrict__ c2b,
        int* __restrict__ out) {
    __shared__ f16 latH[MB * 128];
    __shared__ f16 latL[MB * 128];
    __shared__ unsigned r1K[4][MB]; __shared__ int r1I[4][MB];
    __shared__ unsigned r2K[4][MB]; __shared__ int r2I[4][MB];

    const int t    = threadIdx.x;
    const int wave = t >> 6;
    const int lane = t & 63;
    const int quad = lane >> 4;
    const int l15  = lane & 15;
    const int row0 = blockIdx.x * MB;

    {   // Stage latent 128x128: scale -2, split h/l, XOR-swizzle 16-B units.
        const float4* src = (const float4*)(latent + (size_t)row0 * D_DIM);
#pragma unroll
        for (int i = 0; i < 8; ++i) {
            int g  = i * 256 + t;          // float8 index in [0,2048)
            int r  = g >> 4;               // row (16 float8 per row)
            int c8 = g & 15;               // logical 16-B column
            float4 v0 = src[2 * g];
            float4 v1 = src[2 * g + 1];
            float xs[8] = {v0.x, v0.y, v0.z, v0.w, v1.x, v1.y, v1.z, v1.w};
            f16x8 hv, lv;
#pragma unroll
            for (int c = 0; c < 8; ++c) {
                float x = -2.0f * xs[c];
                f16 h = (f16)x;
                hv[c] = h;
                lv[c] = (f16)(x - (float)h);
            }
            int pc = ((c8 ^ (r & 15)) << 3);
            *(f16x8*)&latH[r * 128 + pc] = hv;
            *(f16x8*)&latL[r * 128 + pc] = lv;
        }
    }
    __syncthreads();

    unsigned b1[32], b2[32];
#pragma unroll
    for (int i = 0; i < 32; ++i) { b1[i] = 0xFFFFFFFFu; b2[i] = 0xFFFFFFFFu; }

    const int wbase = wave * KW;
    // Packed-B element offset of the next step's load: uniform +1024/step.
    unsigned offB = (unsigned)(wave * 32 * 4) * 1024u + (unsigned)(lane * 8);

    // Named ping-pong regs — never address-taken.
    f16x8 Ba0, Ba1, Ba2, Ba3, Bb0, Bb1, Bb2, Bb3;
    f32x4 a00, a01, a10, a11, a20, a21, a30, a31;
    f32x4 a40, a41, a50, a51, a60, a61, a70, a71;

#define PFB(P) \
    P##0 = *(const f16x8*)(chp + offB); \
    P##1 = *(const f16x8*)(clp + offB); \
    P##2 = *(const f16x8*)(chp + offB + 512); \
    P##3 = *(const f16x8*)(clp + offB + 512);

#define MF(d, a, b) d = __builtin_amdgcn_mfma_f32_16x16x32_f16(a, b, d, 0, 0, 0);
#define MFC(d, a, b, c) d = __builtin_amdgcn_mfma_f32_16x16x32_f16(a, b, c, 0, 0, 0);

// One row-group: 2 LDS loads + 6 MFMAs (3 splits x 2 n-groups), accumulate.
#define GRP(P, g, pc_) \
    ah_ = *(const f16x8*)&latH[((g) * 16 + l15) * 128 + (pc_)]; \
    al_ = *(const f16x8*)&latL[((g) * 16 + l15) * 128 + (pc_)]; \
    MF(a##g##0, ah_, P##0) MF(a##g##0, ah_, P##1) MF(a##g##0, al_, P##0) \
    MF(a##g##1, ah_, P##2) MF(a##g##1, ah_, P##3) MF(a##g##1, al_, P##2)

// Row-group, ds==0 form: first MFMA of each acc takes the c2 broadcast as C.
#define GRP0(P, g, pc_) \
    ah_ = *(const f16x8*)&latH[((g) * 16 + l15) * 128 + (pc_)]; \
    al_ = *(const f16x8*)&latL[((g) * 16 + l15) * 128 + (pc_)]; \
    MFC(a##g##0, ah_, P##0, cvec0) MF(a##g##0, ah_, P##1) MF(a##g##0, al_, P##0) \
    MFC(a##g##1, ah_, P##2, cvec1) MF(a##g##1, ah_, P##3) MF(a##g##1, al_, P##2)

// ds>=1 step: 8 row-groups. Prio 1 across the MFMA cluster (T5).
#define STEP(P, ds) { \
    __builtin_amdgcn_s_setprio(1); \
    const int pc_ = ((((ds) << 2) + quad) ^ l15) << 3; \
    f16x8 ah_, al_; \
    GRP(P, 0, pc_) GRP(P, 1, pc_) GRP(P, 2, pc_) GRP(P, 3, pc_) \
    GRP(P, 4, pc_) GRP(P, 5, pc_) GRP(P, 6, pc_) GRP(P, 7, pc_) \
    __builtin_amdgcn_s_setprio(0); }

// ds==0 step: acc re-init through the C operand (no INIT pass).
#define STEP0(P) { \
    __builtin_amdgcn_s_setprio(1); \
    const int pc_ = (quad ^ l15) << 3; \
    f16x8 ah_, al_; \
    GRP0(P, 0, pc_) GRP0(P, 1, pc_) GRP0(P, 2, pc_) GRP0(P, 3, pc_) \
    GRP0(P, 4, pc_) GRP0(P, 5, pc_) GRP0(P, 6, pc_) GRP0(P, 7, pc_) \
    __builtin_amdgcn_s_setprio(0); }

// Merged dual-key top-2 insert (exact top-2 of {b1,b2,kA,kB}), min3/med3 form.
#define INS2(sA, sB, slot) { \
    unsigned kA_ = (__float_as_uint(sA) & 0xFFFFFFC0u) | kn0; \
    unsigned kB_ = (__float_as_uint(sB) & 0xFFFFFFC0u) | kn1; \
    unsigned ob1_ = b1[slot]; \
    unsigned lo_ = kA_ < kB_ ? kA_ : kB_; \
    unsigned hi_ = kA_ < kB_ ? kB_ : kA_; \
    unsigned m1_ = hi_ < ob1_ ? hi_ : ob1_; \
    unsigned med_ = lo_ > m1_ ? lo_ : m1_; \
    b1[slot] = lo_ < ob1_ ? lo_ : ob1_; \
    b2[slot] = med_ < b2[slot] ? med_ : b2[slot]; }

#define INSP(A0, A1, m) \
    INS2(A0[0], A1[0], (m) * 4 + 0) INS2(A0[1], A1[1], (m) * 4 + 1) \
    INS2(A0[2], A1[2], (m) * 4 + 2) INS2(A0[3], A1[3], (m) * 4 + 3)

    // Prime: load (kt=0, ds=0) into Ba; offB -> (0, ds1).
    PFB(Ba)
    offB += 1024;
    float cv0 = c2b[wbase + l15];
    float cv1 = c2b[wbase + 16 + l15];

#pragma unroll 1
    for (int kt = 0; kt < KW / 32; ++kt) {
        f32x4 cvec0 = (f32x4){cv0, cv0, cv0, cv0};
        f32x4 cvec1 = (f32x4){cv1, cv1, cv1, cv1};

        int ktn = (kt + 1) & 31;    // wraps at end; value then unused
        float cvn0 = c2b[wbase + ktn * 32 + l15];
        float cvn1 = c2b[wbase + ktn * 32 + 16 + l15];

        PFB(Bb) offB += 1024; STEP0(Ba)     // loads (kt,ds1); C-init from cvec
        PFB(Ba) offB += 1024; STEP(Bb, 1)   // loads (kt,ds2)
        PFB(Bb) offB += 1024; STEP(Ba, 2)   // loads (kt,ds3); offB -> (kt+1,ds0)
        PFB(Ba)                             // loads (kt+1,ds0); kt=31 overrun
                                            // lands in clp/c2b (alloc'd, unused)
        offB += 1024;                       // -> (kt+1,ds1)
        STEP(Bb, 3)

        const unsigned kn0 = (unsigned)(kt * 2);
        const unsigned kn1 = kn0 + 1u;
        INSP(a00, a01, 0) INSP(a10, a11, 1)
        INSP(a20, a21, 2) INSP(a30, a31, 3)
        INSP(a40, a41, 4) INSP(a50, a51, 5)
        INSP(a60, a61, 6) INSP(a70, a71, 7)

        cv0 = cvn0; cv1 = cvn1;
    }

    // Quad butterfly: merge two sorted-2 (key,idx) lists per step.
#pragma unroll
    for (int m = 0; m < 8; ++m)
#pragma unroll
        for (int r = 0; r < 4; ++r) {
            unsigned k1 = b1[m * 4 + r], k2 = b2[m * 4 + r];
            int i1 = ((wave * 64 + (int)(k1 & 63u)) << 4) | l15;
            int i2 = ((wave * 64 + (int)(k2 & 63u)) << 4) | l15;
#pragma unroll
            for (int msk = 1; msk < 16; msk <<= 1) {
                unsigned ok1 = (unsigned)__shfl_xor((int)k1, msk, 64);
                int      oi1 = __shfl_xor(i1, msk, 64);
                unsigned ok2 = (unsigned)__shfl_xor((int)k2, msk, 64);
                int      oi2 = __shfl_xor(i2, msk, 64);
                bool ow = ok1 < k1;
                unsigned w1k = ow ? ok1 : k1; int w1i = ow ? oi1 : i1;
                unsigned lsk = ow ? k1 : ok1; int lsi = ow ? i1 : oi1;
                unsigned wsk = ow ? ok2 : k2; int wsi = ow ? oi2 : i2;
                bool sw = lsk < wsk;
                k1 = w1k; i1 = w1i;
                k2 = sw ? lsk : wsk; i2 = sw ? lsi : wsi;
            }
            if (l15 == 0) {
                int p = m * 16 + quad * 4 + r;
                r1K[wave][p] = k1; r1I[wave][p] = i1;
                r2K[wave][p] = k2; r2I[wave][p] = i2;
            }
        }
    __syncthreads();

    // ---- fused epilogue: cross-wave merge + gap-gated exact fp64 rescore ----
    if (t < MB) {
        unsigned k1 = r1K[0][t], k2 = r2K[0][t];
        int      i1 = r1I[0][t], i2 = r2I[0][t];
#pragma unroll
        for (int w = 1; w < 4; ++w) {
            unsigned ok1 = r1K[w][t], ok2 = r2K[w][t];
            int      oi1 = r1I[w][t], oi2 = r2I[w][t];
            bool ow = ok1 < k1;
            unsigned w1k = ow ? ok1 : k1; int w1i = ow ? oi1 : i1;
            unsigned lsk = ow ? k1 : ok1; int lsi = ow ? i1 : oi1;
            unsigned wsk = ow ? ok2 : k2; int wsi = ow ? oi2 : i2;
            bool sw = lsk < wsk;
            k1 = w1k; i1 = w1i;
            k2 = sw ? lsk : wsk; i2 = sw ? lsi : wsi;
        }
        // Gap test: keys are monotone bit-patterns of positive fp32 scores;
        // (k2-k1) in ulps >> worst-case split error (~100 ulp + 128 ulp
        // quantization) proves i1 is the exact argmin.
        if (k2 - k1 > GAP_ULP) {
            out[row0 + t] = i1;
        } else {
            // Exact fp64 rescore of the two candidates. Tie -> smaller index.
            const float* x  = latent + (size_t)(row0 + t) * D_DIM;
            const float* ca = coords + (size_t)i1 * D_DIM;
            const float* cb = coords + (size_t)i2 * D_DIM;
            double d1 = 0.0, d2 = 0.0;
#pragma unroll
            for (int d = 0; d < D_DIM; d += 4) {
                float4 xv = *(const float4*)(x + d);
                float4 av = *(const float4*)(ca + d);
                float4 bv = *(const float4*)(cb + d);
                double e;
                e = (double)xv.x - (double)av.x; d1 += e * e;
                e = (double)xv.y - (double)av.y; d1 += e * e;
                e = (double)xv.z - (double)av.z; d1 += e * e;
                e = (double)xv.w - (double)av.w; d1 += e * e;
                e = (double)xv.x - (double)bv.x; d2 += e * e;
                e = (double)xv.y - (double)bv.y; d2 += e * e;
                e = (double)xv.z - (double)bv.z; d2 += e * e;
                e = (double)xv.w - (double)bv.w; d2 += e * e;
            }
            bool second = (d2 < d1) || (d2 == d1 && i2 < i1);
            out[row0 + t] = second ? i2 : i1;
        }
    }
}

// ---------------------------------------------------------------------------
extern "C" void kernel_launch(void* const* d_in, const int* in_sizes, int n_in,
                              void* d_out, int out_size, void* d_ws, size_t ws_size,
                              hipStream_t stream) {
    const float* latent = (const float*)d_in[0];
    const float* coords = (const float*)d_in[1];
    int* out = (int*)d_out;

    // ws: chp [K*D] f16 | clp [K*D] f16 | c2b [K] f32
    f16*   chp = (f16*)d_ws;
    f16*   clp = chp + (size_t)K_CENT * D_DIM;
    float* c2b = (float*)(clp + (size_t)K_CENT * D_DIM);

    split_pack_c2<<<dim3(K_CENT * D_DIM / 1024), dim3(256), 0, stream>>>(coords, chp, clp, c2b);
    argmin_mfma<<<dim3(N_PTS / MB), dim3(256), 0, stream>>>(latent, coords, chp, clp, c2b, out);
}

// Round 14
// 231.330 us; speedup vs baseline: 2.4362x; 2.4362x over previous
//
#include <hip/hip_runtime.h>

// CentroidPool: N=65536 x K=4096 x D=128 fp32 -> argmin_k ||x - c_k|| (int32).
// Stage 1: f16x3-split MFMA GEMM (xh*ch + xh*cl + xl*ch, fp32 acc = c2 init),
//   top-2 via sortable packed keys, register ping-pong B pipeline, B pre-packed
//   in per-(tile,step,lane) fragment order -> every B load 64x16B coalesced.
// ROUND-27: REVERT to the r25 optimum (225.8us). r26's MB=128 spilled (4th
//   confirmation of the register wall: >~152 live regs -> catastrophic spill;
//   the unified VGPR/AGPR file at the 2-wave tier cannot hold 64-acc + 64-
//   tracker liveness). All axes now closed by measurement:
//   occupancy (r15/r17), rows/wave (r26), MFMA shape (r21), acc-dbuf (r14),
//   weave (r19), stagger (r20). r25 state: INS min3/med3 (2.5 VALU/key),
//   C-operand acc init, branchless loop, setprio MFMA clusters, fused
//   gap-gated fp64 rescore, vectorized split_pack.
//   Counters at r25: MfmaUtil 58 + VALUBusy 42 ~= issue-saturated; 1.67x the
//   f16x3 MFMA floor (99.4us) -- remaining gap is the irreducible per-wave
//   instruction stream at the forced 2-wave occupancy.
// Output written directly by argmin blocks.

typedef _Float16 f16;
typedef f16  f16x4 __attribute__((ext_vector_type(4)));
typedef f16  f16x8 __attribute__((ext_vector_type(8)));
typedef float f32x4 __attribute__((ext_vector_type(4)));

constexpr int N_PTS  = 65536;
constexpr int K_CENT = 4096;
constexpr int D_DIM  = 128;
constexpr int MB     = 64;     // points per block (4 waves share them)
constexpr int KW     = 1024;   // centroids per wave (waves split K 4-ways)
constexpr float SOFF = 256.0f; // score offset => strictly positive scores
constexpr unsigned GAP_ULP = 2048u; // rescore-skip margin (see r24 note)

// ---------------------------------------------------------------------------
// Split coords to f16 h/l, pack into fragment order, compute c2+SOFF.
// Vectorized: one float4 (4 dims of one cent) per thread.
// dst = ((gt*4 + ds)*2 + n)*512 + lane*8 + j, j0 = d0&7 in {0,4} -> f16x4.
// c2: 32 threads per cent, pure shuffle reduce (masks 1..16 stay in-group).
// ---------------------------------------------------------------------------
__global__ __launch_bounds__(256) void split_pack_c2(const float* __restrict__ c,
                                                     f16* __restrict__ chp,
                                                     f16* __restrict__ clp,
                                                     float* __restrict__ c2b) {
    const int t = threadIdx.x;
    const int idx = blockIdx.x * 256 + t;      // float4 index over K*D/4
    const int cent = idx >> 5;                 // 32 float4 per cent
    const int d0 = (idx & 31) * 4;             // starting dim
    float4 v = *(const float4*)(c + (size_t)cent * D_DIM + d0);
    f16 h0 = (f16)v.x, h1 = (f16)v.y, h2 = (f16)v.z, h3 = (f16)v.w;
    f16 l0 = (f16)(v.x - (float)h0), l1 = (f16)(v.y - (float)h1);
    f16 l2 = (f16)(v.z - (float)h2), l3 = (f16)(v.w - (float)h3);
    int gt = cent >> 5, n = (cent >> 4) & 1, l15c = cent & 15;
    int ds = d0 >> 5, quad = (d0 >> 3) & 3, j0 = d0 & 7;
    int lane = quad * 16 + l15c;
    int dst = ((gt * 4 + ds) * 2 + n) * 512 + lane * 8 + j0;
    *(f16x4*)(chp + dst) = (f16x4){h0, h1, h2, h3};
    *(f16x4*)(clp + dst) = (f16x4){l0, l1, l2, l3};
    // c2 reduction across the cent's 32 threads.
    float s = v.x * v.x + v.y * v.y + v.z * v.z + v.w * v.w;
#pragma unroll
    for (int m = 1; m < 32; m <<= 1) s += __shfl_xor(s, m, 64);
    if ((t & 31) == 0) c2b[cent] = s + SOFF;
}

// ---------------------------------------------------------------------------
// Stage 1 + fused rescore. Block = 4 waves x 64 points; latent (-2x) split h/l
// in XOR-swizzled LDS. Wave w scans cents [w*1024,(w+1)*1024) in 32-wide
// k-tiles (2 n-groups). Ping-pong invariant: Ba = (kt, ds0), offB -> (kt,ds1).
// key = (bits(score)&~63)|kn, kn = kt*2+n (6b); cent = (wave*64+kn)*16 + l15.
// Epilogue: t<64 merges block top-2; gap>GAP_ULP proves top-1 -> write it,
// else exact fp64 rescore (tie -> smaller index).
// ---------------------------------------------------------------------------
__global__ __launch_bounds__(256, 2) void argmin_mfma(
        const float* __restrict__ latent,
        const float* __restrict__ coords,
        const f16*   __restrict__ chp,    // packed B hi
        const f16*   __restrict__ clp,    // packed B lo
        const float* __restrict__ c2b,
        int* __restrict__ out) {
    __shared__ f16 latH[MB * 128];
    __shared__ f16 latL[MB * 128];
    __shared__ unsigned r1K[4][MB]; __shared__ int r1I[4][MB];
    __shared__ unsigned r2K[4][MB]; __shared__ int r2I[4][MB];

    const int t    = threadIdx.x;
    const int wave = t >> 6;
    const int lane = t & 63;
    const int quad = lane >> 4;
    const int l15  = lane & 15;
    const int row0 = blockIdx.x * MB;

    {   // Stage latent: scale -2, split h/l, XOR-swizzle 16-B units.
        const float4* src = (const float4*)(latent + (size_t)row0 * D_DIM);
#pragma unroll
        for (int i = 0; i < 4; ++i) {
            int g  = i * 256 + t;          // float8 index in [0,1024)
            int r  = g >> 4;               // row (16 float8 per row)
            int c8 = g & 15;               // logical 16-B column
            float4 v0 = src[2 * g];
            float4 v1 = src[2 * g + 1];
            float xs[8] = {v0.x, v0.y, v0.z, v0.w, v1.x, v1.y, v1.z, v1.w};
            f16x8 hv, lv;
#pragma unroll
            for (int c = 0; c < 8; ++c) {
                float x = -2.0f * xs[c];
                f16 h = (f16)x;
                hv[c] = h;
                lv[c] = (f16)(x - (float)h);
            }
            int pc = ((c8 ^ (r & 15)) << 3);
            *(f16x8*)&latH[r * 128 + pc] = hv;
            *(f16x8*)&latL[r * 128 + pc] = lv;
        }
    }
    __syncthreads();

    unsigned b1[16], b2[16];
#pragma unroll
    for (int i = 0; i < 16; ++i) { b1[i] = 0xFFFFFFFFu; b2[i] = 0xFFFFFFFFu; }

    const int wbase = wave * KW;
    // Packed-B element offset of the next step's load: uniform +1024/step.
    unsigned offB = (unsigned)(wave * 32 * 4) * 1024u + (unsigned)(lane * 8);

    // Named ping-pong regs — never address-taken.
    f16x8 Ba0, Ba1, Ba2, Ba3, Bb0, Bb1, Bb2, Bb3;
    f32x4 a00, a01, a10, a11, a20, a21, a30, a31;

#define PFB(P) \
    P##0 = *(const f16x8*)(chp + offB); \
    P##1 = *(const f16x8*)(clp + offB); \
    P##2 = *(const f16x8*)(chp + offB + 512); \
    P##3 = *(const f16x8*)(clp + offB + 512);

#define MF(d, a, b) d = __builtin_amdgcn_mfma_f32_16x16x32_f16(a, b, d, 0, 0, 0);
#define MFC(d, a, b, c) d = __builtin_amdgcn_mfma_f32_16x16x32_f16(a, b, c, 0, 0, 0);

// ds>=1 step: accumulate into live accs. Prio 1 across the MFMA cluster.
#define STEP(P, ds) { \
    __builtin_amdgcn_s_setprio(1); \
    const int pc_ = ((((ds) << 2) + quad) ^ l15) << 3; \
    f16x8 ah_, al_; \
    ah_ = *(const f16x8*)&latH[(     l15) * 128 + pc_]; \
    al_ = *(const f16x8*)&latL[(     l15) * 128 + pc_]; \
    MF(a00, ah_, P##0) MF(a00, ah_, P##1) MF(a00, al_, P##0) \
    MF(a01, ah_, P##2) MF(a01, ah_, P##3) MF(a01, al_, P##2) \
    ah_ = *(const f16x8*)&latH[(16 + l15) * 128 + pc_]; \
    al_ = *(const f16x8*)&latL[(16 + l15) * 128 + pc_]; \
    MF(a10, ah_, P##0) MF(a10, ah_, P##1) MF(a10, al_, P##0) \
    MF(a11, ah_, P##2) MF(a11, ah_, P##3) MF(a11, al_, P##2) \
    ah_ = *(const f16x8*)&latH[(32 + l15) * 128 + pc_]; \
    al_ = *(const f16x8*)&latL[(32 + l15) * 128 + pc_]; \
    MF(a20, ah_, P##0) MF(a20, ah_, P##1) MF(a20, al_, P##0) \
    MF(a21, ah_, P##2) MF(a21, ah_, P##3) MF(a21, al_, P##2) \
    ah_ = *(const f16x8*)&latH[(48 + l15) * 128 + pc_]; \
    al_ = *(const f16x8*)&latL[(48 + l15) * 128 + pc_]; \
    MF(a30, ah_, P##0) MF(a30, ah_, P##1) MF(a30, al_, P##0) \
    MF(a31, ah_, P##2) MF(a31, ah_, P##3) MF(a31, al_, P##2) \
    __builtin_amdgcn_s_setprio(0); }

// ds==0 step: each acc's FIRST MFMA takes the c2 broadcast as C (no INIT pass).
#define STEP0(P) { \
    __builtin_amdgcn_s_setprio(1); \
    const int pc_ = (quad ^ l15) << 3; \
    f16x8 ah_, al_; \
    ah_ = *(const f16x8*)&latH[(     l15) * 128 + pc_]; \
    al_ = *(const f16x8*)&latL[(     l15) * 128 + pc_]; \
    MFC(a00, ah_, P##0, cvec0) MF(a00, ah_, P##1) MF(a00, al_, P##0) \
    MFC(a01, ah_, P##2, cvec1) MF(a01, ah_, P##3) MF(a01, al_, P##2) \
    ah_ = *(const f16x8*)&latH[(16 + l15) * 128 + pc_]; \
    al_ = *(const f16x8*)&latL[(16 + l15) * 128 + pc_]; \
    MFC(a10, ah_, P##0, cvec0) MF(a10, ah_, P##1) MF(a10, al_, P##0) \
    MFC(a11, ah_, P##2, cvec1) MF(a11, ah_, P##3) MF(a11, al_, P##2) \
    ah_ = *(const f16x8*)&latH[(32 + l15) * 128 + pc_]; \
    al_ = *(const f16x8*)&latL[(32 + l15) * 128 + pc_]; \
    MFC(a20, ah_, P##0, cvec0) MF(a20, ah_, P##1) MF(a20, al_, P##0) \
    MFC(a21, ah_, P##2, cvec1) MF(a21, ah_, P##3) MF(a21, al_, P##2) \
    ah_ = *(const f16x8*)&latH[(48 + l15) * 128 + pc_]; \
    al_ = *(const f16x8*)&latL[(48 + l15) * 128 + pc_]; \
    MFC(a30, ah_, P##0, cvec0) MF(a30, ah_, P##1) MF(a30, al_, P##0) \
    MFC(a31, ah_, P##2, cvec1) MF(a31, ah_, P##3) MF(a31, al_, P##2) \
    __builtin_amdgcn_s_setprio(0); }

// Merged dual-key top-2 insert (exact top-2 of {b1,b2,kA,kB}), canonical
// min3/med3 form: nb1 = min(min(kA,kB), ob1)            [v_min3_u32]
//                 med = max(min(kA,kB), min(max(kA,kB), ob1))  [v_med3_u32]
//                 nb2 = min(ob2, med).
#define INS2(sA, sB, slot) { \
    unsigned kA_ = (__float_as_uint(sA) & 0xFFFFFFC0u) | kn0; \
    unsigned kB_ = (__float_as_uint(sB) & 0xFFFFFFC0u) | kn1; \
    unsigned ob1_ = b1[slot]; \
    unsigned lo_ = kA_ < kB_ ? kA_ : kB_; \
    unsigned hi_ = kA_ < kB_ ? kB_ : kA_; \
    unsigned m1_ = hi_ < ob1_ ? hi_ : ob1_; \
    unsigned med_ = lo_ > m1_ ? lo_ : m1_; \
    b1[slot] = lo_ < ob1_ ? lo_ : ob1_; \
    b2[slot] = med_ < b2[slot] ? med_ : b2[slot]; }

#define INSP(A0, A1, m) \
    INS2(A0[0], A1[0], (m) * 4 + 0) INS2(A0[1], A1[1], (m) * 4 + 1) \
    INS2(A0[2], A1[2], (m) * 4 + 2) INS2(A0[3], A1[3], (m) * 4 + 3)

    // Prime: load (kt=0, ds=0) into Ba; offB -> (0, ds1).
    PFB(Ba)
    offB += 1024;
    float cv0 = c2b[wbase + l15];
    float cv1 = c2b[wbase + 16 + l15];

#pragma unroll 1
    for (int kt = 0; kt < KW / 32; ++kt) {
        f32x4 cvec0 = (f32x4){cv0, cv0, cv0, cv0};
        f32x4 cvec1 = (f32x4){cv1, cv1, cv1, cv1};

        int ktn = (kt + 1) & 31;    // wraps at end; value then unused
        float cvn0 = c2b[wbase + ktn * 32 + l15];
        float cvn1 = c2b[wbase + ktn * 32 + 16 + l15];

        PFB(Bb) offB += 1024; STEP0(Ba)     // loads (kt,ds1); C-init from cvec
        PFB(Ba) offB += 1024; STEP(Bb, 1)   // loads (kt,ds2)
        PFB(Bb) offB += 1024; STEP(Ba, 2)   // loads (kt,ds3); offB -> (kt+1,ds0)
        PFB(Ba)                             // loads (kt+1,ds0); at kt=31 the
                                            // overrun lands in clp/c2b (alloc'd,
                                            // values unused) -> branchless loop
        offB += 1024;                       // -> (kt+1,ds1)
        STEP(Bb, 3)

        const unsigned kn0 = (unsigned)(kt * 2);
        const unsigned kn1 = kn0 + 1u;
        INSP(a00, a01, 0) INSP(a10, a11, 1)
        INSP(a20, a21, 2) INSP(a30, a31, 3)

        cv0 = cvn0; cv1 = cvn1;
    }

    // Quad butterfly: merge two sorted-2 (key,idx) lists per step.
#pragma unroll
    for (int m = 0; m < 4; ++m)
#pragma unroll
        for (int r = 0; r < 4; ++r) {
            unsigned k1 = b1[m * 4 + r], k2 = b2[m * 4 + r];
            int i1 = ((wave * 64 + (int)(k1 & 63u)) << 4) | l15;
            int i2 = ((wave * 64 + (int)(k2 & 63u)) << 4) | l15;
#pragma unroll
            for (int msk = 1; msk < 16; msk <<= 1) {
                unsigned ok1 = (unsigned)__shfl_xor((int)k1, msk, 64);
                int      oi1 = __shfl_xor(i1, msk, 64);
                unsigned ok2 = (unsigned)__shfl_xor((int)k2, msk, 64);
                int      oi2 = __shfl_xor(i2, msk, 64);
                bool ow = ok1 < k1;
                unsigned w1k = ow ? ok1 : k1; int w1i = ow ? oi1 : i1;
                unsigned lsk = ow ? k1 : ok1; int lsi = ow ? i1 : oi1;
                unsigned wsk = ow ? ok2 : k2; int wsi = ow ? oi2 : i2;
                bool sw = lsk < wsk;
                k1 = w1k; i1 = w1i;
                k2 = sw ? lsk : wsk; i2 = sw ? lsi : wsi;
            }
            if (l15 == 0) {
                int p = m * 16 + quad * 4 + r;
                r1K[wave][p] = k1; r1I[wave][p] = i1;
                r2K[wave][p] = k2; r2I[wave][p] = i2;
            }
        }
    __syncthreads();

    // ---- fused epilogue: cross-wave merge + gap-gated exact fp64 rescore ----
    if (t < MB) {
        unsigned k1 = r1K[0][t], k2 = r2K[0][t];
        int      i1 = r1I[0][t], i2 = r2I[0][t];
#pragma unroll
        for (int w = 1; w < 4; ++w) {
            unsigned ok1 = r1K[w][t], ok2 = r2K[w][t];
            int      oi1 = r1I[w][t], oi2 = r2I[w][t];
            bool ow = ok1 < k1;
            unsigned w1k = ow ? ok1 : k1; int w1i = ow ? oi1 : i1;
            unsigned lsk = ow ? k1 : ok1; int lsi = ow ? i1 : oi1;
            unsigned wsk = ow ? ok2 : k2; int wsi = ow ? oi2 : i2;
            bool sw = lsk < wsk;
            k1 = w1k; i1 = w1i;
            k2 = sw ? lsk : wsk; i2 = sw ? lsi : wsi;
        }
        // Gap test: keys are monotone bit-patterns of positive fp32 scores;
        // (k2-k1) in ulps >> worst-case split error (~100 ulp + 128 ulp
        // quantization) proves i1 is the exact argmin.
        if (k2 - k1 > GAP_ULP) {
            out[row0 + t] = i1;
        } else {
            // Exact fp64 rescore of the two candidates. Tie -> smaller index.
            const float* x  = latent + (size_t)(row0 + t) * D_DIM;
            const float* ca = coords + (size_t)i1 * D_DIM;
            const float* cb = coords + (size_t)i2 * D_DIM;
            double d1 = 0.0, d2 = 0.0;
#pragma unroll
            for (int d = 0; d < D_DIM; d += 4) {
                float4 xv = *(const float4*)(x + d);
                float4 av = *(const float4*)(ca + d);
                float4 bv = *(const float4*)(cb + d);
                double e;
                e = (double)xv.x - (double)av.x; d1 += e * e;
                e = (double)xv.y - (double)av.y; d1 += e * e;
                e = (double)xv.z - (double)av.z; d1 += e * e;
                e = (double)xv.w - (double)av.w; d1 += e * e;
                e = (double)xv.x - (double)bv.x; d2 += e * e;
                e = (double)xv.y - (double)bv.y; d2 += e * e;
                e = (double)xv.z - (double)bv.z; d2 += e * e;
                e = (double)xv.w - (double)bv.w; d2 += e * e;
            }
            bool second = (d2 < d1) || (d2 == d1 && i2 < i1);
            out[row0 + t] = second ? i2 : i1;
        }
    }
}

// ---------------------------------------------------------------------------
extern "C" void kernel_launch(void* const* d_in, const int* in_sizes, int n_in,
                              void* d_out, int out_size, void* d_ws, size_t ws_size,
                              hipStream_t stream) {
    const float* latent = (const float*)d_in[0];
    const float* coords = (const float*)d_in[1];
    int* out = (int*)d_out;

    // ws: chp [K*D] f16 | clp [K*D] f16 | c2b [K] f32
    f16*   chp = (f16*)d_ws;
    f16*   clp = chp + (size_t)K_CENT * D_DIM;
    float* c2b = (float*)(clp + (size_t)K_CENT * D_DIM);

    split_pack_c2<<<dim3(K_CENT * D_DIM / 1024), dim3(256), 0, stream>>>(coords, chp, clp, c2b);
    argmin_mfma<<<dim3(N_PTS / MB), dim3(256), 0, stream>>>(latent, coords, chp, clp, c2b, out);
}

// Round 15
// 196.830 us; speedup vs baseline: 2.8632x; 1.1753x over previous
//
#include <hip/hip_runtime.h>

// CentroidPool: N=65536 x K=4096 x D=128 fp32 -> argmin_k ||x - c_k|| (int32).
// Stage 1: f16x2-split MFMA GEMM (xh*ch + xh*cl = xh*c EXACT; the xl*c term is
//   dropped and bounded), top-2 via sortable packed keys, register ping-pong B
//   pipeline, B pre-packed in fragment order (every load 64x16B coalesced).
// ROUND-28: cut the MFMA floor itself. r27 counters: MFMA-busy = 98us = the
//   3-split floor exactly; wall 166us = floor + 68us non-overlapped
//   VALU/LDS/load stream (all overlap levers closed by r14-r26). Dropping the
//   xl*ch MFMA (-33% MFMA work, floor 99.4 -> 66.3us) leaves score error
//   |sum 2*xl_d*c_d| <= ~0.1 worst-case (f16 remainder of -2x, gaussian-tail
//   weighted; c in [0,1)) -> inter-candidate gap error <= 0.2. The r24
//   gap-gate absorbs it soundly: GAP_ULP 2048 -> 24576 (0.75 d2-units,
//   >=3.5x worst case); closer pairs take the exact fp64 rescore (latency of
//   that loop was already paid by ~every wave -- the gate saved bandwidth).
//   latL deleted (LDS 36.9 -> 20.5KB, staging halved, ds_reads/kt 32 -> 16).
//   Registers strictly decrease -> no spill risk. Everything else = r25/r27.
// Output written directly by argmin blocks.

typedef _Float16 f16;
typedef f16  f16x4 __attribute__((ext_vector_type(4)));
typedef f16  f16x8 __attribute__((ext_vector_type(8)));
typedef float f32x4 __attribute__((ext_vector_type(4)));

constexpr int N_PTS  = 65536;
constexpr int K_CENT = 4096;
constexpr int D_DIM  = 128;
constexpr int MB     = 64;     // points per block (4 waves share them)
constexpr int KW     = 1024;   // centroids per wave (waves split K 4-ways)
constexpr float SOFF = 256.0f; // score offset => strictly positive scores
constexpr unsigned GAP_ULP = 24576u; // 0.75 d2-units @score~384; >=3.5x the
                                     // 2-term worst-case gap error (~0.2)

// ---------------------------------------------------------------------------
// Split coords to f16 h/l, pack into fragment order, compute c2+SOFF.
// Vectorized: one float4 (4 dims of one cent) per thread.
// dst = ((gt*4 + ds)*2 + n)*512 + lane*8 + j, j0 = d0&7 in {0,4} -> f16x4.
// c2: 32 threads per cent, pure shuffle reduce (masks 1..16 stay in-group).
// ---------------------------------------------------------------------------
__global__ __launch_bounds__(256) void split_pack_c2(const float* __restrict__ c,
                                                     f16* __restrict__ chp,
                                                     f16* __restrict__ clp,
                                                     float* __restrict__ c2b) {
    const int t = threadIdx.x;
    const int idx = blockIdx.x * 256 + t;      // float4 index over K*D/4
    const int cent = idx >> 5;                 // 32 float4 per cent
    const int d0 = (idx & 31) * 4;             // starting dim
    float4 v = *(const float4*)(c + (size_t)cent * D_DIM + d0);
    f16 h0 = (f16)v.x, h1 = (f16)v.y, h2 = (f16)v.z, h3 = (f16)v.w;
    f16 l0 = (f16)(v.x - (float)h0), l1 = (f16)(v.y - (float)h1);
    f16 l2 = (f16)(v.z - (float)h2), l3 = (f16)(v.w - (float)h3);
    int gt = cent >> 5, n = (cent >> 4) & 1, l15c = cent & 15;
    int ds = d0 >> 5, quad = (d0 >> 3) & 3, j0 = d0 & 7;
    int lane = quad * 16 + l15c;
    int dst = ((gt * 4 + ds) * 2 + n) * 512 + lane * 8 + j0;
    *(f16x4*)(chp + dst) = (f16x4){h0, h1, h2, h3};
    *(f16x4*)(clp + dst) = (f16x4){l0, l1, l2, l3};
    // c2 reduction across the cent's 32 threads.
    float s = v.x * v.x + v.y * v.y + v.z * v.z + v.w * v.w;
#pragma unroll
    for (int m = 1; m < 32; m <<= 1) s += __shfl_xor(s, m, 64);
    if ((t & 31) == 0) c2b[cent] = s + SOFF;
}

// ---------------------------------------------------------------------------
// Stage 1 + fused rescore. Block = 4 waves x 64 points; latent (-2x) f16-hi
// part in XOR-swizzled LDS (xh*(ch+cl) = xh*c exact; xl*c bounded + gated).
// Wave w scans cents [w*1024,(w+1)*1024) in 32-wide k-tiles (2 n-groups).
// Ping-pong invariant: Ba = (kt, ds0), offB -> (kt,ds1).
// key = (bits(score)&~63)|kn, kn = kt*2+n (6b); cent = (wave*64+kn)*16 + l15.
// Epilogue: t<64 merges block top-2; gap>GAP_ULP proves top-1 -> write it,
// else exact fp64 rescore (tie -> smaller index).
// ---------------------------------------------------------------------------
__global__ __launch_bounds__(256, 2) void argmin_mfma(
        const float* __restrict__ latent,
        const float* __restrict__ coords,
        const f16*   __restrict__ chp,    // packed B hi
        const f16*   __restrict__ clp,    // packed B lo
        const float* __restrict__ c2b,
        int* __restrict__ out) {
    __shared__ f16 latH[MB * 128];
    __shared__ unsigned r1K[4][MB]; __shared__ int r1I[4][MB];
    __shared__ unsigned r2K[4][MB]; __shared__ int r2I[4][MB];

    const int t    = threadIdx.x;
    const int wave = t >> 6;
    const int lane = t & 63;
    const int quad = lane >> 4;
    const int l15  = lane & 15;
    const int row0 = blockIdx.x * MB;

    {   // Stage latent: scale -2, take f16 hi part, XOR-swizzle 16-B units.
        const float4* src = (const float4*)(latent + (size_t)row0 * D_DIM);
#pragma unroll
        for (int i = 0; i < 4; ++i) {
            int g  = i * 256 + t;          // float8 index in [0,1024)
            int r  = g >> 4;               // row (16 float8 per row)
            int c8 = g & 15;               // logical 16-B column
            float4 v0 = src[2 * g];
            float4 v1 = src[2 * g + 1];
            float xs[8] = {v0.x, v0.y, v0.z, v0.w, v1.x, v1.y, v1.z, v1.w};
            f16x8 hv;
#pragma unroll
            for (int c = 0; c < 8; ++c) hv[c] = (f16)(-2.0f * xs[c]);
            int pc = ((c8 ^ (r & 15)) << 3);
            *(f16x8*)&latH[r * 128 + pc] = hv;
        }
    }
    __syncthreads();

    unsigned b1[16], b2[16];
#pragma unroll
    for (int i = 0; i < 16; ++i) { b1[i] = 0xFFFFFFFFu; b2[i] = 0xFFFFFFFFu; }

    const int wbase = wave * KW;
    // Packed-B element offset of the next step's load: uniform +1024/step.
    unsigned offB = (unsigned)(wave * 32 * 4) * 1024u + (unsigned)(lane * 8);

    // Named ping-pong regs — never address-taken.
    f16x8 Ba0, Ba1, Ba2, Ba3, Bb0, Bb1, Bb2, Bb3;
    f32x4 a00, a01, a10, a11, a20, a21, a30, a31;

#define PFB(P) \
    P##0 = *(const f16x8*)(chp + offB); \
    P##1 = *(const f16x8*)(clp + offB); \
    P##2 = *(const f16x8*)(chp + offB + 512); \
    P##3 = *(const f16x8*)(clp + offB + 512);

#define MF(d, a, b) d = __builtin_amdgcn_mfma_f32_16x16x32_f16(a, b, d, 0, 0, 0);
#define MFC(d, a, b, c) d = __builtin_amdgcn_mfma_f32_16x16x32_f16(a, b, c, 0, 0, 0);

// ds>=1 step: 2 MFMAs per acc (xh*ch + xh*cl). Prio 1 across the cluster.
#define STEP(P, ds) { \
    __builtin_amdgcn_s_setprio(1); \
    const int pc_ = ((((ds) << 2) + quad) ^ l15) << 3; \
    f16x8 ah_; \
    ah_ = *(const f16x8*)&latH[(     l15) * 128 + pc_]; \
    MF(a00, ah_, P##0) MF(a00, ah_, P##1) \
    MF(a01, ah_, P##2) MF(a01, ah_, P##3) \
    ah_ = *(const f16x8*)&latH[(16 + l15) * 128 + pc_]; \
    MF(a10, ah_, P##0) MF(a10, ah_, P##1) \
    MF(a11, ah_, P##2) MF(a11, ah_, P##3) \
    ah_ = *(const f16x8*)&latH[(32 + l15) * 128 + pc_]; \
    MF(a20, ah_, P##0) MF(a20, ah_, P##1) \
    MF(a21, ah_, P##2) MF(a21, ah_, P##3) \
    ah_ = *(const f16x8*)&latH[(48 + l15) * 128 + pc_]; \
    MF(a30, ah_, P##0) MF(a30, ah_, P##1) \
    MF(a31, ah_, P##2) MF(a31, ah_, P##3) \
    __builtin_amdgcn_s_setprio(0); }

// ds==0 step: each acc's FIRST MFMA takes the c2 broadcast as C (no INIT pass).
#define STEP0(P) { \
    __builtin_amdgcn_s_setprio(1); \
    const int pc_ = (quad ^ l15) << 3; \
    f16x8 ah_; \
    ah_ = *(const f16x8*)&latH[(     l15) * 128 + pc_]; \
    MFC(a00, ah_, P##0, cvec0) MF(a00, ah_, P##1) \
    MFC(a01, ah_, P##2, cvec1) MF(a01, ah_, P##3) \
    ah_ = *(const f16x8*)&latH[(16 + l15) * 128 + pc_]; \
    MFC(a10, ah_, P##0, cvec0) MF(a10, ah_, P##1) \
    MFC(a11, ah_, P##2, cvec1) MF(a11, ah_, P##3) \
    ah_ = *(const f16x8*)&latH[(32 + l15) * 128 + pc_]; \
    MFC(a20, ah_, P##0, cvec0) MF(a20, ah_, P##1) \
    MFC(a21, ah_, P##2, cvec1) MF(a21, ah_, P##3) \
    ah_ = *(const f16x8*)&latH[(48 + l15) * 128 + pc_]; \
    MFC(a30, ah_, P##0, cvec0) MF(a30, ah_, P##1) \
    MFC(a31, ah_, P##2, cvec1) MF(a31, ah_, P##3) \
    __builtin_amdgcn_s_setprio(0); }

// Merged dual-key top-2 insert (exact top-2 of {b1,b2,kA,kB}), canonical
// min3/med3 form: nb1 = min(min(kA,kB), ob1)            [v_min3_u32]
//                 med = max(min(kA,kB), min(max(kA,kB), ob1))  [v_med3_u32]
//                 nb2 = min(ob2, med).
#define INS2(sA, sB, slot) { \
    unsigned kA_ = (__float_as_uint(sA) & 0xFFFFFFC0u) | kn0; \
    unsigned kB_ = (__float_as_uint(sB) & 0xFFFFFFC0u) | kn1; \
    unsigned ob1_ = b1[slot]; \
    unsigned lo_ = kA_ < kB_ ? kA_ : kB_; \
    unsigned hi_ = kA_ < kB_ ? kB_ : kA_; \
    unsigned m1_ = hi_ < ob1_ ? hi_ : ob1_; \
    unsigned med_ = lo_ > m1_ ? lo_ : m1_; \
    b1[slot] = lo_ < ob1_ ? lo_ : ob1_; \
    b2[slot] = med_ < b2[slot] ? med_ : b2[slot]; }

#define INSP(A0, A1, m) \
    INS2(A0[0], A1[0], (m) * 4 + 0) INS2(A0[1], A1[1], (m) * 4 + 1) \
    INS2(A0[2], A1[2], (m) * 4 + 2) INS2(A0[3], A1[3], (m) * 4 + 3)

    // Prime: load (kt=0, ds=0) into Ba; offB -> (0, ds1).
    PFB(Ba)
    offB += 1024;
    float cv0 = c2b[wbase + l15];
    float cv1 = c2b[wbase + 16 + l15];

#pragma unroll 1
    for (int kt = 0; kt < KW / 32; ++kt) {
        f32x4 cvec0 = (f32x4){cv0, cv0, cv0, cv0};
        f32x4 cvec1 = (f32x4){cv1, cv1, cv1, cv1};

        int ktn = (kt + 1) & 31;    // wraps at end; value then unused
        float cvn0 = c2b[wbase + ktn * 32 + l15];
        float cvn1 = c2b[wbase + ktn * 32 + 16 + l15];

        PFB(Bb) offB += 1024; STEP0(Ba)     // loads (kt,ds1); C-init from cvec
        PFB(Ba) offB += 1024; STEP(Bb, 1)   // loads (kt,ds2)
        PFB(Bb) offB += 1024; STEP(Ba, 2)   // loads (kt,ds3); offB -> (kt+1,ds0)
        PFB(Ba)                             // loads (kt+1,ds0); at kt=31 the
                                            // overrun lands in clp/c2b (alloc'd,
                                            // values unused) -> branchless loop
        offB += 1024;                       // -> (kt+1,ds1)
        STEP(Bb, 3)

        const unsigned kn0 = (unsigned)(kt * 2);
        const unsigned kn1 = kn0 + 1u;
        INSP(a00, a01, 0) INSP(a10, a11, 1)
        INSP(a20, a21, 2) INSP(a30, a31, 3)

        cv0 = cvn0; cv1 = cvn1;
    }

    // Quad butterfly: merge two sorted-2 (key,idx) lists per step.
#pragma unroll
    for (int m = 0; m < 4; ++m)
#pragma unroll
        for (int r = 0; r < 4; ++r) {
            unsigned k1 = b1[m * 4 + r], k2 = b2[m * 4 + r];
            int i1 = ((wave * 64 + (int)(k1 & 63u)) << 4) | l15;
            int i2 = ((wave * 64 + (int)(k2 & 63u)) << 4) | l15;
#pragma unroll
            for (int msk = 1; msk < 16; msk <<= 1) {
                unsigned ok1 = (unsigned)__shfl_xor((int)k1, msk, 64);
                int      oi1 = __shfl_xor(i1, msk, 64);
                unsigned ok2 = (unsigned)__shfl_xor((int)k2, msk, 64);
                int      oi2 = __shfl_xor(i2, msk, 64);
                bool ow = ok1 < k1;
                unsigned w1k = ow ? ok1 : k1; int w1i = ow ? oi1 : i1;
                unsigned lsk = ow ? k1 : ok1; int lsi = ow ? i1 : oi1;
                unsigned wsk = ow ? ok2 : k2; int wsi = ow ? oi2 : i2;
                bool sw = lsk < wsk;
                k1 = w1k; i1 = w1i;
                k2 = sw ? lsk : wsk; i2 = sw ? lsi : wsi;
            }
            if (l15 == 0) {
                int p = m * 16 + quad * 4 + r;
                r1K[wave][p] = k1; r1I[wave][p] = i1;
                r2K[wave][p] = k2; r2I[wave][p] = i2;
            }
        }
    __syncthreads();

    // ---- fused epilogue: cross-wave merge + gap-gated exact fp64 rescore ----
    if (t < MB) {
        unsigned k1 = r1K[0][t], k2 = r2K[0][t];
        int      i1 = r1I[0][t], i2 = r2I[0][t];
#pragma unroll
        for (int w = 1; w < 4; ++w) {
            unsigned ok1 = r1K[w][t], ok2 = r2K[w][t];
            int      oi1 = r1I[w][t], oi2 = r2I[w][t];
            bool ow = ok1 < k1;
            unsigned w1k = ow ? ok1 : k1; int w1i = ow ? oi1 : i1;
            unsigned lsk = ow ? k1 : ok1; int lsi = ow ? i1 : oi1;
            unsigned wsk = ow ? ok2 : k2; int wsi = ow ? oi2 : i2;
            bool sw = lsk < wsk;
            k1 = w1k; i1 = w1i;
            k2 = sw ? lsk : wsk; i2 = sw ? lsi : wsi;
        }
        // Gap test: keys are monotone bit-patterns of positive fp32 scores;
        // (k2-k1) in ulps must exceed 2x the one-candidate worst-case error
        // of the 2-term estimate (~0.1 -> ~3300 ulp) + accum/quantization.
        // GAP_ULP = 24576 (~0.75) gives >=3.5x margin.
        if (k2 - k1 > GAP_ULP) {
            out[row0 + t] = i1;
        } else {
            // Exact fp64 rescore of the two candidates. Tie -> smaller index.
            const float* x  = latent + (size_t)(row0 + t) * D_DIM;
            const float* ca = coords + (size_t)i1 * D_DIM;
            const float* cb = coords + (size_t)i2 * D_DIM;
            double d1 = 0.0, d2 = 0.0;
#pragma unroll
            for (int d = 0; d < D_DIM; d += 4) {
                float4 xv = *(const float4*)(x + d);
                float4 av = *(const float4*)(ca + d);
                float4 bv = *(const float4*)(cb + d);
                double e;
                e = (double)xv.x - (double)av.x; d1 += e * e;
                e = (double)xv.y - (double)av.y; d1 += e * e;
                e = (double)xv.z - (double)av.z; d1 += e * e;
                e = (double)xv.w - (double)av.w; d1 += e * e;
                e = (double)xv.x - (double)bv.x; d2 += e * e;
                e = (double)xv.y - (double)bv.y; d2 += e * e;
                e = (double)xv.z - (double)bv.z; d2 += e * e;
                e = (double)xv.w - (double)bv.w; d2 += e * e;
            }
            bool second = (d2 < d1) || (d2 == d1 && i2 < i1);
            out[row0 + t] = second ? i2 : i1;
        }
    }
}

// ---------------------------------------------------------------------------
extern "C" void kernel_launch(void* const* d_in, const int* in_sizes, int n_in,
                              void* d_out, int out_size, void* d_ws, size_t ws_size,
                              hipStream_t stream) {
    const float* latent = (const float*)d_in[0];
    const float* coords = (const float*)d_in[1];
    int* out = (int*)d_out;

    // ws: chp [K*D] f16 | clp [K*D] f16 | c2b [K] f32
    f16*   chp = (f16*)d_ws;
    f16*   clp = chp + (size_t)K_CENT * D_DIM;
    float* c2b = (float*)(clp + (size_t)K_CENT * D_DIM);

    split_pack_c2<<<dim3(K_CENT * D_DIM / 1024), dim3(256), 0, stream>>>(coords, chp, clp, c2b);
    argmin_mfma<<<dim3(N_PTS / MB), dim3(256), 0, stream>>>(latent, coords, chp, clp, c2b, out);
}